// Round 1
// baseline (1702.119 us; speedup 1.0000x reference)
//
#include <hip/hip_runtime.h>

namespace {

constexpr int NTH = 512;   // threads per block (8 waves)
constexpr int NB  = 512;   // GRU batch (original T)
constexpr int HID = 128;
constexpr int G3  = 384;
constexpr int TG  = 6;     // gate rows per thread
constexpr int SS  = 128;   // scan steps (original B)
constexpr int CH  = 20;    // padded LDS chunk stride (16 data + 4 pad floats)

template <int CTRL>
__device__ __forceinline__ float add_dpp(float v) {
    // v + (v moved by DPP ctrl); invalid source lanes contribute 0 (bound_ctrl=1)
    int moved = __builtin_amdgcn_update_dpp(0, __float_as_int(v), CTRL, 0xf, 0xf, true);
    return v + __int_as_float(moved);
}

// sum over the 8 lanes of each aligned 8-lane group; valid where (lane&7)==7
__device__ __forceinline__ float wave_red8(float v) {
    v = add_dpp<0x111>(v);  // row_shr:1
    v = add_dpp<0x112>(v);  // row_shr:2
    v = add_dpp<0x114>(v);  // row_shr:4
    return v;
}

__device__ __forceinline__ float dot4acc(float4 a, float4 b, float acc) {
    acc = fmaf(a.x, b.x, acc);
    acc = fmaf(a.y, b.y, acc);
    acc = fmaf(a.z, b.z, acc);
    acc = fmaf(a.w, b.w, acc);
    return acc;
}

__device__ __forceinline__ float fsigmoid(float x) {
    x = fminf(fmaxf(x, -30.f), 30.f);
    return 1.f / (1.f + __expf(-x));
}

__device__ __forceinline__ float ftanh(float x) {
    x = fminf(fmaxf(x, -15.f), 15.f);
    const float e = __expf(2.f * x);
    return 1.f - 2.f / (e + 1.f);
}

__global__ __launch_bounds__(NTH) void gru3_fused(
    const float* __restrict__ xin,
    const float* __restrict__ wih0, const float* __restrict__ whh0,
    const float* __restrict__ bih0, const float* __restrict__ bhh0,
    const float* __restrict__ wih1, const float* __restrict__ whh1,
    const float* __restrict__ bih1, const float* __restrict__ bhh1,
    const float* __restrict__ wih2, const float* __restrict__ whh2,
    const float* __restrict__ bih2, const float* __restrict__ bhh2,
    float* __restrict__ out)
{
    // x/h tiles in padded-chunk layout: [row][chunk(8)][CH], 16 data floats per chunk.
    __shared__ __align__(16) float xb[2][2 * 8 * CH];
    __shared__ __align__(16) float hb[2 * 8 * CH];
    __shared__ float pxl[2][G3];      // reduced input-proj preacts
    __shared__ float ghl[2][G3];      // reduced hidden-proj preacts
    __shared__ float bsum[2 * HID];   // b_ih+b_hh for r,z
    __shared__ float bin_[HID];       // b_ih (n gate)
    __shared__ float bhn_[HID];       // b_hh (n gate)

    const int tid  = threadIdx.x;
    const int kgrp = tid & 7;        // k-chunk of 16 (lane bits 0..2)
    const int gt   = tid >> 3;       // 0..63 gate tile
    const int g0   = gt * TG;
    const int row0 = blockIdx.x * 2;

    float4 wih[TG][4];  // 96 floats of w_ih  (zero-padded past kin)
    float4 whh[TG][4];  // 96 floats of w_hh

    for (int layer = 0; layer < 3; ++layer) {
        const float *wi, *wh, *bi, *bh, *xs;
        float* yd;
        int kin;
        if (layer == 0)      { wi = wih0; wh = whh0; bi = bih0; bh = bhh0; xs = xin; yd = out; kin = 64;  }
        else if (layer == 1) { wi = wih1; wh = whh1; bi = bih1; bh = bhh1; xs = out; yd = out; kin = HID; }
        else                 { wi = wih2; wh = whh2; bi = bih2; bh = bhh2; xs = out; yd = out; kin = HID; }

        // ---- stage this layer's weights into registers (once per layer) ----
        #pragma unroll
        for (int gg = 0; gg < TG; ++gg) {
            const int g = g0 + gg;
            #pragma unroll
            for (int q = 0; q < 4; ++q) {
                const int k = kgrp * 16 + q * 4;
                whh[gg][q] = *reinterpret_cast<const float4*>(wh + g * HID + k);
                if (k < kin)
                    wih[gg][q] = *reinterpret_cast<const float4*>(wi + g * kin + k);
                else
                    wih[gg][q] = make_float4(0.f, 0.f, 0.f, 0.f);
            }
        }

        // ---- biases, zero h and x buffers ----
        for (int i = tid; i < 2 * HID; i += NTH) bsum[i] = bi[i] + bh[i];
        for (int i = tid; i < HID; i += NTH) { bin_[i] = bi[256 + i]; bhn_[i] = bh[256 + i]; }
        for (int i = tid; i < 2 * 8 * CH; i += NTH) { hb[i] = 0.f; xb[0][i] = 0.f; xb[1][i] = 0.f; }
        __syncthreads();
        if (tid < 256) {  // stage x[0]
            const int n = tid >> 7, j = tid & 127;
            if (j < kin)
                xb[0][n * (8 * CH) + (j >> 4) * CH + (j & 15)] = xs[(0 * NB + row0 + n) * kin + j];
        }
        __syncthreads();

        float ypend = 0.f;   // deferred y store (gate threads), hides store drain
        bool  have_y = false;

        for (int s = 0; s < SS; ++s) {
            // -- issue global traffic early: prefetch x[s+1], store y[s-1] --
            float xpref = 0.f;
            if (tid >= 256) {
                const int t2 = tid - 256;
                const int n = t2 >> 7, j = t2 & 127;
                if (s + 1 < SS && j < kin)
                    xpref = xs[((s + 1) * NB + row0 + n) * kin + j];
            } else if (have_y) {
                const int n = tid >> 7, j = tid & 127;
                yd[((s - 1) * NB + row0 + n) * HID + j] = ypend;
            }

            // -- P1 (x @ w_ih.T) and P2 (h @ w_hh.T), k-split over 8 lane groups --
            float accp[2][TG], accg[2][TG];
            #pragma unroll
            for (int n = 0; n < 2; ++n)
                #pragma unroll
                for (int gg = 0; gg < TG; ++gg) { accp[n][gg] = 0.f; accg[n][gg] = 0.f; }

            const float* xcur = xb[s & 1];
            #pragma unroll
            for (int q = 0; q < 4; ++q) {
                const int off = kgrp * CH + q * 4;
                const float4 x0 = *reinterpret_cast<const float4*>(xcur + off);
                const float4 x1 = *reinterpret_cast<const float4*>(xcur + 8 * CH + off);
                const float4 h0 = *reinterpret_cast<const float4*>(hb + off);
                const float4 h1 = *reinterpret_cast<const float4*>(hb + 8 * CH + off);
                #pragma unroll
                for (int gg = 0; gg < TG; ++gg) {
                    accp[0][gg] = dot4acc(x0, wih[gg][q], accp[0][gg]);
                    accp[1][gg] = dot4acc(x1, wih[gg][q], accp[1][gg]);
                    accg[0][gg] = dot4acc(h0, whh[gg][q], accg[0][gg]);
                    accg[1][gg] = dot4acc(h1, whh[gg][q], accg[1][gg]);
                }
            }

            // -- reduce the 8 k-partials per (row,gate) on the VALU (DPP), stash to LDS --
            #pragma unroll
            for (int n = 0; n < 2; ++n)
                #pragma unroll
                for (int gg = 0; gg < TG; ++gg) {
                    const float rp = wave_red8(accp[n][gg]);
                    const float rg = wave_red8(accg[n][gg]);
                    if (kgrp == 7) { pxl[n][g0 + gg] = rp; ghl[n][g0 + gg] = rg; }
                }
            __syncthreads();  // B1

            // -- gate math (waves 0-3) | x prefetch -> LDS (waves 4-7) --
            if (tid < 256) {
                const int n = tid >> 7, j = tid & 127;
                const float pr = pxl[n][j]       + ghl[n][j]       + bsum[j];
                const float pz = pxl[n][j + 128] + ghl[n][j + 128] + bsum[j + 128];
                const float gn = ghl[n][j + 256] + bhn_[j];
                const float pn = pxl[n][j + 256] + bin_[j];
                const float r  = fsigmoid(pr);
                const float z  = fsigmoid(pz);
                const float nn = ftanh(pn + r * gn);
                const int hoff = n * (8 * CH) + (j >> 4) * CH + (j & 15);
                const float hold = hb[hoff];
                const float hnew = (1.f - z) * nn + z * hold;
                hb[hoff] = hnew;
                ypend = hnew;
                have_y = true;
            } else {
                const int t2 = tid - 256;
                const int n = t2 >> 7, j = t2 & 127;
                if (s + 1 < SS && j < kin)
                    xb[(s + 1) & 1][n * (8 * CH) + (j >> 4) * CH + (j & 15)] = xpref;
            }
            __syncthreads();  // B2
        }

        // flush last step's y
        if (tid < 256) {
            const int n = tid >> 7, j = tid & 127;
            yd[((SS - 1) * NB + row0 + n) * HID + j] = ypend;
        }
        __syncthreads();
    }
}

}  // namespace

extern "C" void kernel_launch(void* const* d_in, const int* in_sizes, int n_in,
                              void* d_out, int out_size, void* d_ws, size_t ws_size,
                              hipStream_t stream)
{
    (void)in_sizes; (void)n_in; (void)d_ws; (void)ws_size; (void)out_size;
    gru3_fused<<<dim3(NB / 2), dim3(NTH), 0, stream>>>(
        (const float*)d_in[0],
        (const float*)d_in[1], (const float*)d_in[2],
        (const float*)d_in[3], (const float*)d_in[4],
        (const float*)d_in[5], (const float*)d_in[6],
        (const float*)d_in[7], (const float*)d_in[8],
        (const float*)d_in[9], (const float*)d_in[10],
        (const float*)d_in[11], (const float*)d_in[12],
        (float*)d_out);
}

// Round 2
// 686.488 us; speedup vs baseline: 2.4795x; 2.4795x over previous
//
#include <hip/hip_runtime.h>

namespace {

constexpr int NTH = 512;   // threads per block (fused + rec)
constexpr int NB  = 512;   // GRU batch (original T)
constexpr int HID = 128;
constexpr int G3  = 384;
constexpr int SS  = 128;   // scan steps (original B)
constexpr int CH  = 20;    // padded LDS chunk stride (16 data + 4 pad floats)

typedef float f32x2 __attribute__((ext_vector_type(2)));

__device__ __forceinline__ f32x2 pk_fma(f32x2 a, f32x2 b, f32x2 c) {
#if __has_builtin(__builtin_elementwise_fma)
    return __builtin_elementwise_fma(a, b, c);
#else
    f32x2 r; r.x = fmaf(a.x, b.x, c.x); r.y = fmaf(a.y, b.y, c.y); return r;
#endif
}

template <int CTRL>
__device__ __forceinline__ float add_dpp(float v) {
    int moved = __builtin_amdgcn_update_dpp(0, __float_as_int(v), CTRL, 0xf, 0xf, true);
    return v + __int_as_float(moved);
}

// sum over the 8 lanes of each aligned 8-lane group; valid where (lane&7)==7
__device__ __forceinline__ float wave_red8(float v) {
    v = add_dpp<0x111>(v);  // row_shr:1
    v = add_dpp<0x112>(v);  // row_shr:2
    v = add_dpp<0x114>(v);  // row_shr:4
    return v;
}

__device__ __forceinline__ float dot4acc(float4 a, float4 b, float acc) {
    acc = fmaf(a.x, b.x, acc);
    acc = fmaf(a.y, b.y, acc);
    acc = fmaf(a.z, b.z, acc);
    acc = fmaf(a.w, b.w, acc);
    return acc;
}

__device__ __forceinline__ float fsigmoid(float x) {
    x = fminf(fmaxf(x, -30.f), 30.f);
    return 1.f / (1.f + __expf(-x));
}

__device__ __forceinline__ float ftanh(float x) {
    x = fminf(fmaxf(x, -15.f), 15.f);
    const float e = __expf(2.f * x);
    return 1.f - 2.f / (e + 1.f);
}

// ============================================================================
// Split path kernel 1: px GEMM.
// px[m][g] = sum_k A[m][k] * W[g][k] + bih[g] + (g<256 ? bhh[g] : 0)
// M = 65536, K = kin (64 or 128), G = 384.
// Block 256 threads; tile BM=128 x BN=128; thread tile 8x8; BK=32.
// ============================================================================
constexpr int BKG = 32;
constexpr int TSTR = 132;  // LDS row stride (128 + 4 pad), 16B-aligned

__global__ __launch_bounds__(256, 4) void px_gemm(
    const float* __restrict__ A,    // [M][kin]
    const float* __restrict__ W,    // [384][kin]
    const float* __restrict__ bih,
    const float* __restrict__ bhh,
    float* __restrict__ px,         // [M][384]
    int kin)
{
    __shared__ __align__(16) float At[BKG * TSTR];  // transposed: At[k][m_local]
    __shared__ __align__(16) float Wt[BKG * TSTR];  // transposed: Wt[k][g_local]

    const int tid = threadIdx.x;
    const int m0  = blockIdx.x * 128;
    const int g0  = blockIdx.y * 128;
    const int tr  = tid >> 4;   // 0..15 row tile
    const int tc  = tid & 15;   // 0..15 gate tile

    f32x2 acc2[8][4];
    #pragma unroll
    for (int i = 0; i < 8; ++i)
        #pragma unroll
        for (int j = 0; j < 4; ++j) acc2[i][j] = f32x2{0.f, 0.f};

    const int srow = tid >> 3;        // 0..31 (row within 32-row pass)
    const int sf4  = (tid & 7) * 4;   // k-offset (float)

    for (int kt = 0; kt < kin; kt += BKG) {
        // ---- stage A,W transposed into LDS ----
        #pragma unroll
        for (int p = 0; p < 4; ++p) {
            const int r = p * 32 + srow;
            const float4 va = *reinterpret_cast<const float4*>(A + (size_t)(m0 + r) * kin + kt + sf4);
            At[(sf4 + 0) * TSTR + r] = va.x;
            At[(sf4 + 1) * TSTR + r] = va.y;
            At[(sf4 + 2) * TSTR + r] = va.z;
            At[(sf4 + 3) * TSTR + r] = va.w;
            const float4 vw = *reinterpret_cast<const float4*>(W + (size_t)(g0 + r) * kin + kt + sf4);
            Wt[(sf4 + 0) * TSTR + r] = vw.x;
            Wt[(sf4 + 1) * TSTR + r] = vw.y;
            Wt[(sf4 + 2) * TSTR + r] = vw.z;
            Wt[(sf4 + 3) * TSTR + r] = vw.w;
        }
        __syncthreads();

        #pragma unroll 8
        for (int kk = 0; kk < BKG; ++kk) {
            const float4 a0 = *reinterpret_cast<const float4*>(&At[kk * TSTR + tr * 8]);
            const float4 a1 = *reinterpret_cast<const float4*>(&At[kk * TSTR + tr * 8 + 4]);
            const float4 w0 = *reinterpret_cast<const float4*>(&Wt[kk * TSTR + tc * 8]);
            const float4 w1 = *reinterpret_cast<const float4*>(&Wt[kk * TSTR + tc * 8 + 4]);
            const f32x2 wp[4] = { f32x2{w0.x, w0.y}, f32x2{w0.z, w0.w},
                                  f32x2{w1.x, w1.y}, f32x2{w1.z, w1.w} };
            const float ar[8] = { a0.x, a0.y, a0.z, a0.w, a1.x, a1.y, a1.z, a1.w };
            #pragma unroll
            for (int i = 0; i < 8; ++i) {
                const f32x2 av = f32x2{ar[i], ar[i]};
                #pragma unroll
                for (int j = 0; j < 4; ++j)
                    acc2[i][j] = pk_fma(av, wp[j], acc2[i][j]);
            }
        }
        __syncthreads();
    }

    // ---- epilogue: add folded bias, store ----
    const int gbase = g0 + tc * 8;
    const bool addz = (g0 < 256);  // r,z blocks fold b_hh too
    float4 b0 = *reinterpret_cast<const float4*>(bih + gbase);
    float4 b1 = *reinterpret_cast<const float4*>(bih + gbase + 4);
    if (addz) {
        const float4 h0 = *reinterpret_cast<const float4*>(bhh + gbase);
        const float4 h1 = *reinterpret_cast<const float4*>(bhh + gbase + 4);
        b0.x += h0.x; b0.y += h0.y; b0.z += h0.z; b0.w += h0.w;
        b1.x += h1.x; b1.y += h1.y; b1.z += h1.z; b1.w += h1.w;
    }
    #pragma unroll
    for (int i = 0; i < 8; ++i) {
        const int m = m0 + tr * 8 + i;
        float4 o0, o1;
        o0.x = acc2[i][0].x + b0.x; o0.y = acc2[i][0].y + b0.y;
        o0.z = acc2[i][1].x + b0.z; o0.w = acc2[i][1].y + b0.w;
        o1.x = acc2[i][2].x + b1.x; o1.y = acc2[i][2].y + b1.y;
        o1.z = acc2[i][3].x + b1.z; o1.w = acc2[i][3].y + b1.w;
        *reinterpret_cast<float4*>(px + (size_t)m * G3 + gbase)     = o0;
        *reinterpret_cast<float4*>(px + (size_t)m * G3 + gbase + 4) = o1;
    }
}

// ============================================================================
// Split path kernel 2: recurrence. One row per block, 512 blocks, 512 threads.
// Per step: gh = h @ w_hh.T (k-split 8 lane groups, DPP reduce), gates, update.
// px already contains x@w_ih.T + b_ih (+ b_hh for r,z).
// ============================================================================
__global__ __launch_bounds__(NTH, 4) void gru_rec(
    const float* __restrict__ px,   // [SS*NB][384]
    const float* __restrict__ whh,  // [384][128]
    const float* __restrict__ bhh,  // [384]
    float* __restrict__ yd)         // [SS][NB][HID]
{
    __shared__ __align__(16) float hb[8 * CH];
    __shared__ float ghl[G3];
    __shared__ float bhn[HID];

    const int tid  = threadIdx.x;
    const int kgrp = tid & 7;
    const int gt   = tid >> 3;     // 0..63
    const int g0   = gt * 6;
    const int row  = blockIdx.x;

    // stage w_hh slice into registers: 6 gates x 16 k
    float4 w[6][4];
    #pragma unroll
    for (int gg = 0; gg < 6; ++gg)
        #pragma unroll
        for (int q = 0; q < 4; ++q)
            w[gg][q] = *reinterpret_cast<const float4*>(whh + (size_t)(g0 + gg) * HID + kgrp * 16 + q * 4);

    for (int i = tid; i < HID; i += NTH) bhn[i] = bhh[256 + i];
    for (int i = tid; i < 8 * CH; i += NTH) hb[i] = 0.f;
    __syncthreads();

    // preload px[0]
    float pxr = 0.f, pxz = 0.f, pxn = 0.f;
    if (tid < HID) {
        const float* p0 = px + (size_t)row * G3 + tid;
        pxr = p0[0]; pxz = p0[128]; pxn = p0[256];
    }

    float ypend = 0.f;
    for (int s = 0; s < SS; ++s) {
        // issue next-step px loads and previous-step y store early
        float nxr = 0.f, nxz = 0.f, nxn = 0.f;
        if (tid < HID) {
            if (s + 1 < SS) {
                const float* p1 = px + ((size_t)(s + 1) * NB + row) * G3 + tid;
                nxr = p1[0]; nxz = p1[128]; nxn = p1[256];
            }
            if (s > 0) yd[((size_t)(s - 1) * NB + row) * HID + tid] = ypend;
        }

        // ---- gh = h @ w_hh.T, k-split over 8 lane groups ----
        f32x2 acc2[6];
        #pragma unroll
        for (int gg = 0; gg < 6; ++gg) acc2[gg] = f32x2{0.f, 0.f};
        #pragma unroll
        for (int q = 0; q < 4; ++q) {
            const float4 h4 = *reinterpret_cast<const float4*>(&hb[kgrp * CH + q * 4]);
            const f32x2 hlo = f32x2{h4.x, h4.y};
            const f32x2 hhi = f32x2{h4.z, h4.w};
            #pragma unroll
            for (int gg = 0; gg < 6; ++gg) {
                const float4 wv = w[gg][q];
                acc2[gg] = pk_fma(hlo, f32x2{wv.x, wv.y}, acc2[gg]);
                acc2[gg] = pk_fma(hhi, f32x2{wv.z, wv.w}, acc2[gg]);
            }
        }
        #pragma unroll
        for (int gg = 0; gg < 6; ++gg) {
            const float r = wave_red8(acc2[gg].x + acc2[gg].y);
            if (kgrp == 7) ghl[g0 + gg] = r;
        }
        __syncthreads();  // B1

        if (tid < HID) {
            const float ghr = ghl[tid];
            const float ghz = ghl[tid + 128];
            const float ghn = ghl[tid + 256] + bhn[tid];
            const float r  = fsigmoid(pxr + ghr);
            const float z  = fsigmoid(pxz + ghz);
            const float nn = ftanh(pxn + r * ghn);
            const int hoff = (tid >> 4) * CH + (tid & 15);
            const float hold = hb[hoff];
            const float hnew = (1.f - z) * nn + z * hold;
            hb[hoff] = hnew;
            ypend = hnew;
            pxr = nxr; pxz = nxz; pxn = nxn;
        }
        __syncthreads();  // B2
    }

    if (tid < HID) yd[((size_t)(SS - 1) * NB + row) * HID + tid] = ypend;
}

// ============================================================================
// Fallback: R1 fused kernel (used only if workspace is too small for px).
// ============================================================================
__global__ __launch_bounds__(NTH) void gru3_fused(
    const float* __restrict__ xin,
    const float* __restrict__ wih0, const float* __restrict__ whh0,
    const float* __restrict__ bih0, const float* __restrict__ bhh0,
    const float* __restrict__ wih1, const float* __restrict__ whh1,
    const float* __restrict__ bih1, const float* __restrict__ bhh1,
    const float* __restrict__ wih2, const float* __restrict__ whh2,
    const float* __restrict__ bih2, const float* __restrict__ bhh2,
    float* __restrict__ out)
{
    __shared__ __align__(16) float xb[2][2 * 8 * CH];
    __shared__ __align__(16) float hb[2 * 8 * CH];
    __shared__ float pxl[2][G3];
    __shared__ float ghl[2][G3];
    __shared__ float bsum[2 * HID];
    __shared__ float bin_[HID];
    __shared__ float bhn_[HID];

    const int tid  = threadIdx.x;
    const int kgrp = tid & 7;
    const int gt   = tid >> 3;
    const int g0   = gt * 6;
    const int row0 = blockIdx.x * 2;

    float4 wih[6][4];
    float4 whh[6][4];

    for (int layer = 0; layer < 3; ++layer) {
        const float *wi, *wh, *bi, *bh, *xs;
        float* yd;
        int kin;
        if (layer == 0)      { wi = wih0; wh = whh0; bi = bih0; bh = bhh0; xs = xin; yd = out; kin = 64;  }
        else if (layer == 1) { wi = wih1; wh = whh1; bi = bih1; bh = bhh1; xs = out; yd = out; kin = HID; }
        else                 { wi = wih2; wh = whh2; bi = bih2; bh = bhh2; xs = out; yd = out; kin = HID; }

        #pragma unroll
        for (int gg = 0; gg < 6; ++gg) {
            const int g = g0 + gg;
            #pragma unroll
            for (int q = 0; q < 4; ++q) {
                const int k = kgrp * 16 + q * 4;
                whh[gg][q] = *reinterpret_cast<const float4*>(wh + g * HID + k);
                if (k < kin)
                    wih[gg][q] = *reinterpret_cast<const float4*>(wi + g * kin + k);
                else
                    wih[gg][q] = make_float4(0.f, 0.f, 0.f, 0.f);
            }
        }

        for (int i = tid; i < 2 * HID; i += NTH) bsum[i] = bi[i] + bh[i];
        for (int i = tid; i < HID; i += NTH) { bin_[i] = bi[256 + i]; bhn_[i] = bh[256 + i]; }
        for (int i = tid; i < 2 * 8 * CH; i += NTH) { hb[i] = 0.f; xb[0][i] = 0.f; xb[1][i] = 0.f; }
        __syncthreads();
        if (tid < 256) {
            const int n = tid >> 7, j = tid & 127;
            if (j < kin)
                xb[0][n * (8 * CH) + (j >> 4) * CH + (j & 15)] = xs[(0 * NB + row0 + n) * kin + j];
        }
        __syncthreads();

        float ypend = 0.f;
        bool  have_y = false;

        for (int s = 0; s < SS; ++s) {
            float xpref = 0.f;
            if (tid >= 256) {
                const int t2 = tid - 256;
                const int n = t2 >> 7, j = t2 & 127;
                if (s + 1 < SS && j < kin)
                    xpref = xs[((s + 1) * NB + row0 + n) * kin + j];
            } else if (have_y) {
                const int n = tid >> 7, j = tid & 127;
                yd[((s - 1) * NB + row0 + n) * HID + j] = ypend;
            }

            float accp[2][6], accg[2][6];
            #pragma unroll
            for (int n = 0; n < 2; ++n)
                #pragma unroll
                for (int gg = 0; gg < 6; ++gg) { accp[n][gg] = 0.f; accg[n][gg] = 0.f; }

            const float* xcur = xb[s & 1];
            #pragma unroll
            for (int q = 0; q < 4; ++q) {
                const int off = kgrp * CH + q * 4;
                const float4 x0 = *reinterpret_cast<const float4*>(xcur + off);
                const float4 x1 = *reinterpret_cast<const float4*>(xcur + 8 * CH + off);
                const float4 h0 = *reinterpret_cast<const float4*>(hb + off);
                const float4 h1 = *reinterpret_cast<const float4*>(hb + 8 * CH + off);
                #pragma unroll
                for (int gg = 0; gg < 6; ++gg) {
                    accp[0][gg] = dot4acc(x0, wih[gg][q], accp[0][gg]);
                    accp[1][gg] = dot4acc(x1, wih[gg][q], accp[1][gg]);
                    accg[0][gg] = dot4acc(h0, whh[gg][q], accg[0][gg]);
                    accg[1][gg] = dot4acc(h1, whh[gg][q], accg[1][gg]);
                }
            }

            #pragma unroll
            for (int n = 0; n < 2; ++n)
                #pragma unroll
                for (int gg = 0; gg < 6; ++gg) {
                    const float rp = wave_red8(accp[n][gg]);
                    const float rg = wave_red8(accg[n][gg]);
                    if (kgrp == 7) { pxl[n][g0 + gg] = rp; ghl[n][g0 + gg] = rg; }
                }
            __syncthreads();

            if (tid < 256) {
                const int n = tid >> 7, j = tid & 127;
                const float pr = pxl[n][j]       + ghl[n][j]       + bsum[j];
                const float pz = pxl[n][j + 128] + ghl[n][j + 128] + bsum[j + 128];
                const float gn = ghl[n][j + 256] + bhn_[j];
                const float pn = pxl[n][j + 256] + bin_[j];
                const float r  = fsigmoid(pr);
                const float z  = fsigmoid(pz);
                const float nn = ftanh(pn + r * gn);
                const int hoff = n * (8 * CH) + (j >> 4) * CH + (j & 15);
                const float hold = hb[hoff];
                const float hnew = (1.f - z) * nn + z * hold;
                hb[hoff] = hnew;
                ypend = hnew;
                have_y = true;
            } else {
                const int t2 = tid - 256;
                const int n = t2 >> 7, j = t2 & 127;
                if (s + 1 < SS && j < kin)
                    xb[(s + 1) & 1][n * (8 * CH) + (j >> 4) * CH + (j & 15)] = xpref;
            }
            __syncthreads();
        }

        if (tid < 256) {
            const int n = tid >> 7, j = tid & 127;
            yd[((SS - 1) * NB + row0 + n) * HID + j] = ypend;
        }
        __syncthreads();
    }
}

}  // namespace

extern "C" void kernel_launch(void* const* d_in, const int* in_sizes, int n_in,
                              void* d_out, int out_size, void* d_ws, size_t ws_size,
                              hipStream_t stream)
{
    (void)in_sizes; (void)n_in; (void)out_size;
    const float* xin = (const float*)d_in[0];
    const float* wih[3] = { (const float*)d_in[1], (const float*)d_in[5], (const float*)d_in[9]  };
    const float* whh[3] = { (const float*)d_in[2], (const float*)d_in[6], (const float*)d_in[10] };
    const float* bih[3] = { (const float*)d_in[3], (const float*)d_in[7], (const float*)d_in[11] };
    const float* bhh[3] = { (const float*)d_in[4], (const float*)d_in[8], (const float*)d_in[12] };
    float* out = (float*)d_out;

    const size_t need = (size_t)SS * NB * G3 * sizeof(float);  // 96 MB px buffer
    if (ws_size >= need) {
        float* px = (float*)d_ws;
        for (int l = 0; l < 3; ++l) {
            const float* A = (l == 0) ? xin : out;
            const int kin = (l == 0) ? 64 : HID;
            px_gemm<<<dim3((SS * NB) / 128, 3), dim3(256), 0, stream>>>(
                A, wih[l], bih[l], bhh[l], px, kin);
            gru_rec<<<dim3(NB), dim3(NTH), 0, stream>>>(px, whh[l], bhh[l], out);
        }
    } else {
        gru3_fused<<<dim3(NB / 2), dim3(NTH), 0, stream>>>(
            xin, wih[0], whh[0], bih[0], bhh[0],
            wih[1], whh[1], bih[1], bhh[1],
            wih[2], whh[2], bih[2], bhh[2], out);
    }
}